// Round 1
// baseline (1810.227 us; speedup 1.0000x reference)
//
#include <hip/hip_runtime.h>
#include <math.h>

typedef unsigned int uint32;
typedef unsigned short ushort16;

#define NB     4
#define CIN    192
#define MID_C  96
#define OC3    288      // 3*96 stacked theta/phi/g outputs
#define HH     33       // windows per side (264/8)
#define NWIN   (NB*HH*HH)   // 4356
#define PADW   264
#define IMGW   256

// ---------- bf16 helpers ----------
__device__ __forceinline__ ushort16 f2bf(float f) {
    union { float f; uint32 u; } v; v.f = f;
    uint32 u = v.u;
    uint32 r = (u + 0x7fffu + ((u >> 16) & 1u)) >> 16;   // RNE
    return (ushort16)r;
}
__device__ __forceinline__ float bf_lo(uint32 u) {
    union { uint32 u; float f; } v; v.u = (u << 16); return v.f;
}
__device__ __forceinline__ float bf_hi(uint32 u) {
    union { uint32 u; float f; } v; v.u = (u & 0xffff0000u); return v.f;
}

// ---------- K1: fold BN + shift-mask into packed weights ----------
struct PrepArgs {
    const float* w[3];      // (96,192,3,3) theta/phi/g
    const float* b[3];      // (96)
    const float* gamma[3];
    const float* beta[3];
    const float* mean[3];
    const float* var[3];
    const float* w_out;     // (192,96,3,3)
    const float* b_out;     // (192)
    float* Win;             // [192][288]  (c-major, oc contiguous)
    float* beff;            // [288]
    float* Wout;            // [96][192]
    float* bout;            // [192]
};

__global__ __launch_bounds__(256) void prep_kernel(PrepArgs a) {
    int i = blockIdx.x * 256 + threadIdx.x;
    const int khs[5] = {1,1,2,0,1};
    const int kws[5] = {2,0,1,1,1};
    if (i < 192*288) {
        int c   = i / 288;
        int r2  = i % 288;
        int t   = r2 / 96;
        int och = r2 % 96;
        int grp = (c < 152) ? (c / 38) : 4;
        int kh = khs[grp], kw = kws[grp];
        float scale = a.gamma[t][och] / sqrtf(a.var[t][och] + 1e-5f);
        a.Win[i] = a.w[t][(och*192 + c)*9 + kh*3 + kw] * scale;
    } else if (i < 192*288 + 96*192) {
        int j = i - 192*288;
        int c = j / 192;
        int o = j % 192;
        int grp = (c < 76) ? (c / 19) : 4;
        a.Wout[j] = a.w_out[(o*96 + c)*9 + khs[grp]*3 + kws[grp]];
    } else if (i < 192*288 + 96*192 + 480) {
        int j = i - (192*288 + 96*192);
        if (j < 288) {
            int t = j / 96, och = j % 96;
            float scale = a.gamma[t][och] / sqrtf(a.var[t][och] + 1e-5f);
            a.beff[j] = a.beta[t][och] + (a.b[t][och] - a.mean[t][och]) * scale;
        } else {
            a.bout[j - 288] = a.b_out[j - 288];
        }
    }
}

// ---------- K2: fused qkv-conv + window attention ----------
// one block per (batch, window). 256 threads.
// LDS: xs 64x100 fp32 (25600B) + qkv 3x64x98 bf16 (37632B) + shoff (768B) = 64000B
__global__ __launch_bounds__(256) void qkv_attn_kernel(
    const float* __restrict__ x,     // [4][192][256][256]
    const float* __restrict__ Win,   // [192][288]
    const float* __restrict__ beff,  // [288]
    float* __restrict__ attn_sp)     // [4][96][264][264]
{
    __shared__ float    xs[64][100];
    __shared__ ushort16 qkv[3][64][98];
    __shared__ int      shoff[192];

    int blk = blockIdx.x;
    int b   = blk / (HH*HH);
    int rem = blk % (HH*HH);
    int wy  = rem / HH;
    int wx  = rem % HH;
    int tid = threadIdx.x;

    if (tid < 192) {
        int c = tid;
        int grp = (c < 152) ? (c / 38) : 4;
        int dy = 0, dx = 0;
        if (grp == 0) dx = 1; else if (grp == 1) dx = -1;
        else if (grp == 2) dy = 1; else if (grp == 3) dy = -1;
        shoff[c] = dy*10 + dx;
    }

    int p  = tid & 63;                                      // pixel in window
    int g  = __builtin_amdgcn_readfirstlane(tid >> 6);      // 0..3 (wave-uniform)
    int qy = p >> 3, qx = p & 7;
    int pbase = (1 + qy)*10 + (1 + qx);

    float acc[72];
    #pragma unroll
    for (int o = 0; o < 72; ++o) acc[o] = 0.f;

    int gy0 = wy*8 - 1;     // padded-coord of xs row 0
    int gx0 = wx*8 - 1;

    for (int chunk = 0; chunk < 3; ++chunk) {
        __syncthreads();            // protect xs from previous chunk's readers
        for (int i = tid; i < 6400; i += 256) {
            int cc  = i / 100;
            int pos = i % 100;
            int r   = pos / 10, col = pos % 10;
            int c   = chunk*64 + cc;
            int gy  = gy0 + r, gx = gx0 + col;
            float v = 0.f;
            if (gy >= 4 && gy < 260 && gx >= 4 && gx < 260)
                v = x[((b*CIN + c)*IMGW + (gy - 4))*IMGW + (gx - 4)];
            xs[cc][pos] = v;
        }
        __syncthreads();
        const float* Wp = Win + (chunk*64)*OC3 + g*72;
        for (int cc = 0; cc < 64; ++cc) {
            int c = chunk*64 + cc;
            float xv = xs[cc][pbase + shoff[c]];
            const float* w = Wp + cc*OC3;
            #pragma unroll
            for (int o = 0; o < 72; ++o)
                acc[o] = fmaf(w[o], xv, acc[o]);
        }
    }

    // bias + write q/k/v to LDS (bf16)
    #pragma unroll
    for (int o = 0; o < 72; ++o) {
        int oc  = g*72 + o;
        int t   = oc / 96;
        int och = oc % 96;
        qkv[t][p][och] = f2bf(acc[o] + beff[oc]);
    }
    __syncthreads();

    // attention: 512 (head,row) tasks over 256 threads
    for (int task = tid; task < 512; task += 256) {
        int h  = task >> 6;
        int qi = task & 63;
        float qv[12];
        {
            const uint32* qrow = (const uint32*)&qkv[0][qi][h*12];
            #pragma unroll
            for (int cp = 0; cp < 6; ++cp) {
                uint32 u = qrow[cp];
                qv[2*cp]   = bf_lo(u);
                qv[2*cp+1] = bf_hi(u);
            }
        }
        float s[64];
        float m = -1e30f;
        #pragma unroll
        for (int j = 0; j < 64; ++j) {
            const uint32* krow = (const uint32*)&qkv[1][j][h*12];
            float d = 0.f;
            #pragma unroll
            for (int cp = 0; cp < 6; ++cp) {
                uint32 u = krow[cp];
                d = fmaf(qv[2*cp],   bf_lo(u), d);
                d = fmaf(qv[2*cp+1], bf_hi(u), d);
            }
            s[j] = d;
            m = fmaxf(m, d);
        }
        float sum = 0.f;
        #pragma unroll
        for (int j = 0; j < 64; ++j) { s[j] = __expf(s[j] - m); sum += s[j]; }
        float o_[12];
        #pragma unroll
        for (int c2 = 0; c2 < 12; ++c2) o_[c2] = 0.f;
        #pragma unroll
        for (int j = 0; j < 64; ++j) {
            const uint32* vrow = (const uint32*)&qkv[2][j][h*12];
            float pj = s[j];
            #pragma unroll
            for (int cp = 0; cp < 6; ++cp) {
                uint32 u = vrow[cp];
                o_[2*cp]   = fmaf(pj, bf_lo(u), o_[2*cp]);
                o_[2*cp+1] = fmaf(pj, bf_hi(u), o_[2*cp+1]);
            }
        }
        float inv = 1.f / sum;
        int py = wy*8 + (qi >> 3);
        int px = wx*8 + (qi & 7);
        #pragma unroll
        for (int c2 = 0; c2 < 12; ++c2) {
            int ch = h*12 + c2;
            attn_sp[((b*MID_C + ch)*PADW + py)*PADW + px] = o_[c2] * inv;
        }
    }
}

// ---------- K3: out shift-conv + crop ----------
// one block per 8x8 output tile. 256 threads.
__global__ __launch_bounds__(256) void outconv_kernel(
    const float* __restrict__ sp,    // [4][96][264][264]
    const float* __restrict__ Wout,  // [96][192]
    const float* __restrict__ bout,  // [192]
    float* __restrict__ out)         // [4][192][256][256]
{
    __shared__ float xs[96][100];    // 38400B
    __shared__ int   shoff[96];

    int blk = blockIdx.x;            // 4*32*32
    int b   = blk >> 10;
    int rem = blk & 1023;
    int ty  = rem >> 5;
    int tx  = rem & 31;
    int tid = threadIdx.x;

    if (tid < 96) {
        int c = tid;
        int grp = (c < 76) ? (c / 19) : 4;
        int dy = 0, dx = 0;
        if (grp == 0) dx = 1; else if (grp == 1) dx = -1;
        else if (grp == 2) dy = 1; else if (grp == 3) dy = -1;
        shoff[c] = dy*10 + dx;
    }

    int py0 = ty*8 + 3;   // region row 0 in padded coords (= output row - 1 + 4)
    int px0 = tx*8 + 3;
    for (int i = tid; i < 9600; i += 256) {
        int c   = i / 100;
        int pos = i % 100;
        int r   = pos / 10, col = pos % 10;
        xs[c][pos] = sp[((b*MID_C + c)*PADW + (py0 + r))*PADW + (px0 + col)];
    }
    __syncthreads();

    int p  = tid & 63;
    int g  = __builtin_amdgcn_readfirstlane(tid >> 6);  // 0..3 -> 48 out-ch each
    int qy = p >> 3, qx = p & 7;
    int pbase = (1 + qy)*10 + (1 + qx);

    float acc[48];
    #pragma unroll
    for (int o = 0; o < 48; ++o) acc[o] = bout[g*48 + o];

    for (int c = 0; c < 96; ++c) {
        float xv = xs[c][pbase + shoff[c]];
        const float* w = Wout + c*192 + g*48;
        #pragma unroll
        for (int o = 0; o < 48; ++o)
            acc[o] = fmaf(w[o], xv, acc[o]);
    }

    int oy = ty*8 + qy, ox = tx*8 + qx;
    #pragma unroll
    for (int o = 0; o < 48; ++o) {
        int oc = g*48 + o;
        out[((b*CIN + oc)*IMGW + oy)*IMGW + ox] = acc[o];
    }
}

// ---------- launcher ----------
extern "C" void kernel_launch(void* const* d_in, const int* in_sizes, int n_in,
                              void* d_out, int out_size, void* d_ws, size_t ws_size,
                              hipStream_t stream) {
    const float* x = (const float*)d_in[0];

    PrepArgs a;
    for (int t = 0; t < 3; ++t) {
        a.w[t]     = (const float*)d_in[1 + 6*t];
        a.b[t]     = (const float*)d_in[2 + 6*t];
        a.gamma[t] = (const float*)d_in[3 + 6*t];
        a.beta[t]  = (const float*)d_in[4 + 6*t];
        a.mean[t]  = (const float*)d_in[5 + 6*t];
        a.var[t]   = (const float*)d_in[6 + 6*t];
    }
    a.w_out = (const float*)d_in[19];
    a.b_out = (const float*)d_in[20];

    char* ws = (char*)d_ws;
    float* Win  = (float*)ws;                 // 55296
    float* beff = Win + 192*288;              // 288
    float* Wout = beff + 288;                 // 18432
    float* bout = Wout + 96*192;              // 192
    float* attn_sp = (float*)(ws + 296960);   // [4][96][264][264] fp32, 107MB

    a.Win = Win; a.beff = beff; a.Wout = Wout; a.bout = bout;

    const int prep_items = 192*288 + 96*192 + 480;
    prep_kernel<<<(prep_items + 255)/256, 256, 0, stream>>>(a);
    qkv_attn_kernel<<<NWIN, 256, 0, stream>>>(x, Win, beff, attn_sp);
    outconv_kernel<<<NB*32*32, 256, 0, stream>>>(attn_sp, Wout, bout, (float*)d_out);
}

// Round 2
// 1064.656 us; speedup vs baseline: 1.7003x; 1.7003x over previous
//
#include <hip/hip_runtime.h>
#include <math.h>

typedef unsigned int  uint32;
typedef unsigned short u16;
typedef __attribute__((ext_vector_type(8))) short short8;   // 8 bf16 in 4 VGPRs
typedef __attribute__((ext_vector_type(4))) float f32x4;

#define NB     4
#define CIN    192
#define MID_C  96
#define OC3    288
#define HH     33
#define NWIN   (NB*HH*HH)
#define PADW   264
#define IMGW   256

// ---------- bf16 helpers ----------
__device__ __forceinline__ u16 f2bf(float f) {
    union { float f; uint32 u; } v; v.f = f;
    uint32 u = v.u;
    return (u16)((u + 0x7fffu + ((u >> 16) & 1u)) >> 16);   // RNE
}
__device__ __forceinline__ float bfu_to_f(u16 h) {
    union { uint32 u; float f; } v; v.u = ((uint32)h) << 16; return v.f;
}
__device__ __forceinline__ float bf_lo(uint32 u) {
    union { uint32 u; float f; } v; v.u = (u << 16); return v.f;
}
__device__ __forceinline__ float bf_hi(uint32 u) {
    union { uint32 u; float f; } v; v.u = (u & 0xffff0000u); return v.f;
}

// ---------- K1: fold BN + shift-mask into packed bf16 weights ----------
struct PrepArgs {
    const float* w[3];
    const float* b[3];
    const float* gamma[3];
    const float* beta[3];
    const float* mean[3];
    const float* var[3];
    const float* w_out;
    const float* b_out;
    u16*   Wbf;    // [288 oc][192 c] bf16 (A-operand layout)
    u16*   WbfO;   // [192 oc][96 c]  bf16
    float* beff;   // [288]
    float* bout;   // [192]
};

__global__ __launch_bounds__(256) void prep_kernel(PrepArgs a) {
    int i = blockIdx.x * 256 + threadIdx.x;
    const int khs[5] = {1,1,2,0,1};
    const int kws[5] = {2,0,1,1,1};
    if (i < 288*192) {
        int oc = i / 192, c = i % 192;
        int t = oc / 96, och = oc % 96;
        int grp = (c < 152) ? (c / 38) : 4;
        float scale = a.gamma[t][och] / sqrtf(a.var[t][och] + 1e-5f);
        float v = a.w[t][(och*192 + c)*9 + khs[grp]*3 + kws[grp]] * scale;
        a.Wbf[i] = f2bf(v);
    } else if (i < 288*192 + 192*96) {
        int j = i - 288*192;
        int o = j / 96, c = j % 96;
        int grp = (c < 76) ? (c / 19) : 4;
        a.WbfO[j] = f2bf(a.w_out[(o*96 + c)*9 + khs[grp]*3 + kws[grp]]);
    } else if (i < 288*192 + 192*96 + 480) {
        int j = i - (288*192 + 192*96);
        if (j < 288) {
            int t = j / 96, och = j % 96;
            float scale = a.gamma[t][och] / sqrtf(a.var[t][och] + 1e-5f);
            a.beff[j] = a.beta[t][och] + (a.b[t][och] - a.mean[t][och]) * scale;
        } else {
            a.bout[j - 288] = a.b_out[j - 288];
        }
    }
}

// ---------- K2: MFMA qkv-conv + VALU window attention ----------
// one block per (batch, window). 256 threads = 4 waves (wave = 16-px N-tile).
// LDS: xs 2x32x100 bf16 (12800B) + qkv 3x64x100 bf16 (38400B) + shoff (768B) = 51968B -> 3 blocks/CU
__global__ __launch_bounds__(256, 3) void qkv_attn_kernel(
    const float* __restrict__ x,      // [4][192][256][256]
    const u16*   __restrict__ Wbf,    // [288][192] bf16
    const float* __restrict__ beff,   // [288]
    u16*         __restrict__ attn_sp)// [4][96][264][264] bf16
{
    __shared__ u16 xs[2][32][100];    // hi / lo planes of 32-channel chunk
    __shared__ u16 qkv[3][64][100];
    __shared__ int shoff[192];

    int blk = blockIdx.x;
    int b   = blk / (HH*HH);
    int rem = blk % (HH*HH);
    int wy  = rem / HH;
    int wx  = rem % HH;
    int tid = threadIdx.x;
    int lane = tid & 63;
    int nt   = __builtin_amdgcn_readfirstlane(tid >> 6);   // wave id = N-tile
    int l15  = lane & 15;
    int quad = lane >> 4;

    if (tid < 192) {
        int c = tid;
        int grp = (c < 152) ? (c / 38) : 4;
        int dy = 0, dx = 0;
        if (grp == 0) dx = 1; else if (grp == 1) dx = -1;
        else if (grp == 2) dy = 1; else if (grp == 3) dy = -1;
        shoff[c] = dy*10 + dx;
    }

    int px    = nt*16 + l15;                    // pixel in window (B/D col)
    int pbase = (1 + (px >> 3))*10 + 1 + (px & 7);

    int gy0 = wy*8 - 1;
    int gx0 = wx*8 - 1;

    f32x4 acc[18];
    #pragma unroll
    for (int mt = 0; mt < 18; ++mt) acc[mt] = (f32x4){0.f, 0.f, 0.f, 0.f};

    for (int chunk = 0; chunk < 6; ++chunk) {
        __syncthreads();
        for (int i = tid; i < 3200; i += 256) {
            int cc  = i / 100;
            int pos = i % 100;
            int r   = pos / 10, col = pos % 10;
            int gy  = gy0 + r, gx = gx0 + col;
            float v = 0.f;
            if (gy >= 4 && gy < 260 && gx >= 4 && gx < 260)
                v = x[((b*CIN + chunk*32 + cc)*IMGW + (gy - 4))*IMGW + (gx - 4)];
            u16 h = f2bf(v);
            xs[0][cc][pos] = h;
            xs[1][cc][pos] = f2bf(v - bfu_to_f(h));   // residual -> ~fp32 x
        }
        __syncthreads();

        // B fragments: B[k=c][n=px], k = quad*8 + j
        short8 bh, bl;
        #pragma unroll
        for (int j = 0; j < 8; ++j) {
            int cc  = quad*8 + j;
            int off = pbase + shoff[chunk*32 + cc];
            bh[j] = (short)xs[0][cc][off];
            bl[j] = (short)xs[1][cc][off];
        }
        // A fragments: A[m=oc][k=c], 8 contiguous c -> 16B load (L1-resident)
        const u16* Abase = Wbf + l15*192 + chunk*32 + quad*8;
        #pragma unroll
        for (int mt = 0; mt < 18; ++mt) {
            short8 af = *(const short8*)(Abase + mt*16*192);
            acc[mt] = __builtin_amdgcn_mfma_f32_16x16x32_bf16(af, bh, acc[mt], 0, 0, 0);
            acc[mt] = __builtin_amdgcn_mfma_f32_16x16x32_bf16(af, bl, acc[mt], 0, 0, 0);
        }
    }

    // epilogue: bias, bf16, -> qkv LDS. D: col(l15)=px, row=quad*4+reg = oc%16
    #pragma unroll
    for (int mt = 0; mt < 18; ++mt) {
        #pragma unroll
        for (int r = 0; r < 4; ++r) {
            int oc  = mt*16 + quad*4 + r;
            int t   = oc / 96;
            int och = oc % 96;
            qkv[t][px][och] = f2bf(acc[mt][r] + beff[oc]);
        }
    }
    __syncthreads();

    // attention: 512 (head,row) tasks over 256 threads
    for (int task = tid; task < 512; task += 256) {
        int h  = task >> 6;
        int qi = task & 63;
        float qv[12];
        {
            const uint32* qrow = (const uint32*)&qkv[0][qi][h*12];
            #pragma unroll
            for (int cp = 0; cp < 6; ++cp) {
                uint32 u = qrow[cp];
                qv[2*cp]   = bf_lo(u);
                qv[2*cp+1] = bf_hi(u);
            }
        }
        float s[64];
        float m = -1e30f;
        #pragma unroll
        for (int j = 0; j < 64; ++j) {
            const uint32* krow = (const uint32*)&qkv[1][j][h*12];
            float d = 0.f;
            #pragma unroll
            for (int cp = 0; cp < 6; ++cp) {
                uint32 u = krow[cp];
                d = fmaf(qv[2*cp],   bf_lo(u), d);
                d = fmaf(qv[2*cp+1], bf_hi(u), d);
            }
            s[j] = d;
            m = fmaxf(m, d);
        }
        float sum = 0.f;
        #pragma unroll
        for (int j = 0; j < 64; ++j) { s[j] = __expf(s[j] - m); sum += s[j]; }
        float o_[12];
        #pragma unroll
        for (int c2 = 0; c2 < 12; ++c2) o_[c2] = 0.f;
        #pragma unroll
        for (int j = 0; j < 64; ++j) {
            const uint32* vrow = (const uint32*)&qkv[2][j][h*12];
            float pj = s[j];
            #pragma unroll
            for (int cp = 0; cp < 6; ++cp) {
                uint32 u = vrow[cp];
                o_[2*cp]   = fmaf(pj, bf_lo(u), o_[2*cp]);
                o_[2*cp+1] = fmaf(pj, bf_hi(u), o_[2*cp+1]);
            }
        }
        float inv = 1.f / sum;
        int py  = wy*8 + (qi >> 3);
        int pxx = wx*8 + (qi & 7);
        #pragma unroll
        for (int c2 = 0; c2 < 12; ++c2) {
            int ch = h*12 + c2;
            attn_sp[((b*MID_C + ch)*PADW + py)*PADW + pxx] = f2bf(o_[c2] * inv);
        }
    }
}

// ---------- K3: MFMA out shift-conv + crop ----------
// one block per 8x8 output tile. 256 threads = 4 waves.
__global__ __launch_bounds__(256) void outconv_kernel(
    const u16*   __restrict__ sp,     // [4][96][264][264] bf16
    const u16*   __restrict__ WbfO,   // [192][96] bf16
    const float* __restrict__ bout,   // [192]
    float*       __restrict__ out)    // [4][192][256][256]
{
    __shared__ u16 xs[96][100];       // 19200B
    __shared__ int shoff[96];

    int blk = blockIdx.x;             // 4*32*32
    int b   = blk >> 10;
    int rem = blk & 1023;
    int ty  = rem >> 5;
    int tx  = rem & 31;
    int tid = threadIdx.x;
    int lane = tid & 63;
    int nt   = __builtin_amdgcn_readfirstlane(tid >> 6);
    int l15  = lane & 15;
    int quad = lane >> 4;

    if (tid < 96) {
        int c = tid;
        int grp = (c < 76) ? (c / 19) : 4;
        int dy = 0, dx = 0;
        if (grp == 0) dx = 1; else if (grp == 1) dx = -1;
        else if (grp == 2) dy = 1; else if (grp == 3) dy = -1;
        shoff[c] = dy*10 + dx;
    }

    int py0 = ty*8 + 3;
    int px0 = tx*8 + 3;
    for (int i = tid; i < 9600; i += 256) {
        int c   = i / 100;
        int pos = i % 100;
        int r   = pos / 10, col = pos % 10;
        xs[c][pos] = sp[((b*MID_C + c)*PADW + (py0 + r))*PADW + (px0 + col)];
    }
    __syncthreads();

    int px    = nt*16 + l15;
    int pbase = (1 + (px >> 3))*10 + 1 + (px & 7);

    f32x4 acc[12];
    #pragma unroll
    for (int mt = 0; mt < 12; ++mt) acc[mt] = (f32x4){0.f, 0.f, 0.f, 0.f};

    #pragma unroll
    for (int ks = 0; ks < 3; ++ks) {
        short8 bf;
        #pragma unroll
        for (int j = 0; j < 8; ++j) {
            int cc = ks*32 + quad*8 + j;
            bf[j] = (short)xs[cc][pbase + shoff[cc]];
        }
        const u16* Abase = WbfO + l15*96 + ks*32 + quad*8;
        #pragma unroll
        for (int mt = 0; mt < 12; ++mt) {
            short8 af = *(const short8*)(Abase + mt*16*96);
            acc[mt] = __builtin_amdgcn_mfma_f32_16x16x32_bf16(af, bf, acc[mt], 0, 0, 0);
        }
    }

    int qy = px >> 3, qx = px & 7;
    int oy = ty*8 + qy, ox = tx*8 + qx;
    #pragma unroll
    for (int mt = 0; mt < 12; ++mt) {
        #pragma unroll
        for (int r = 0; r < 4; ++r) {
            int oc = mt*16 + quad*4 + r;
            out[((b*CIN + oc)*IMGW + oy)*IMGW + ox] = acc[mt][r] + bout[oc];
        }
    }
}

// ---------- launcher ----------
extern "C" void kernel_launch(void* const* d_in, const int* in_sizes, int n_in,
                              void* d_out, int out_size, void* d_ws, size_t ws_size,
                              hipStream_t stream) {
    const float* x = (const float*)d_in[0];

    PrepArgs a;
    for (int t = 0; t < 3; ++t) {
        a.w[t]     = (const float*)d_in[1 + 6*t];
        a.b[t]     = (const float*)d_in[2 + 6*t];
        a.gamma[t] = (const float*)d_in[3 + 6*t];
        a.beta[t]  = (const float*)d_in[4 + 6*t];
        a.mean[t]  = (const float*)d_in[5 + 6*t];
        a.var[t]   = (const float*)d_in[6 + 6*t];
    }
    a.w_out = (const float*)d_in[19];
    a.b_out = (const float*)d_in[20];

    char* ws = (char*)d_ws;
    u16*   Wbf     = (u16*)ws;                         // 110592 B
    u16*   WbfO    = (u16*)(ws + 110592);              //  36864 B
    float* beff    = (float*)(ws + 147456);            //   1152 B
    float* bout    = (float*)(ws + 148608);            //    768 B
    u16*   attn_sp = (u16*)(ws + 149504);              // 4*96*264*264*2 = 53526528 B

    a.Wbf = Wbf; a.WbfO = WbfO; a.beff = beff; a.bout = bout;

    const int prep_items = 288*192 + 192*96 + 480;
    prep_kernel<<<(prep_items + 255)/256, 256, 0, stream>>>(a);
    qkv_attn_kernel<<<NWIN, 256, 0, stream>>>(x, Wbf, beff, attn_sp);
    outconv_kernel<<<NB*32*32, 256, 0, stream>>>(attn_sp, WbfO, bout, (float*)d_out);
}